// Round 2
// baseline (2648.196 us; speedup 1.0000x reference)
//
#include <hip/hip_runtime.h>
#include <math.h>

#define HN 512
#define BB 64
#define TT 512
#define IND 256
#define OUTD 256
#define MROWS (BB*TT)   // 32768

// ---------------------------------------------------------------- 8-point DFT
// SGN = -1 : forward (W = exp(-2*pi*i/8)),  SGN = +1 : inverse twiddles
template<int SGN>
__device__ __forceinline__ void dft8(float xr[8], float xi[8]) {
  const float s = 0.70710678118654752440f;
  const float sg = (float)SGN;
  float a0r=xr[0]+xr[4], a0i=xi[0]+xi[4];
  float a1r=xr[1]+xr[5], a1i=xi[1]+xi[5];
  float a2r=xr[2]+xr[6], a2i=xi[2]+xi[6];
  float a3r=xr[3]+xr[7], a3i=xi[3]+xi[7];
  float t0r=xr[0]-xr[4], t0i=xi[0]-xi[4];
  float t1r=xr[1]-xr[5], t1i=xi[1]-xi[5];
  float t2r=xr[2]-xr[6], t2i=xi[2]-xi[6];
  float t3r=xr[3]-xr[7], t3i=xi[3]-xi[7];
  // b_j = t_j * W8^(SGN*j)
  float b1r = s*(t1r - sg*t1i), b1i = s*(sg*t1r + t1i);
  float b2r = -sg*t2i,          b2i = sg*t2r;
  float b3r = -s*(t3r + sg*t3i), b3i = s*(sg*t3r - t3i);
  { // even outputs: DFT4(a0..a3) -> X0,X2,X4,X6
    float c0r=a0r+a2r, c0i=a0i+a2i;
    float c1r=a1r+a3r, c1i=a1i+a3i;
    float d0r=a0r-a2r, d0i=a0i-a2i;
    float e0r=a1r-a3r, e0i=a1i-a3i;
    float d1r=-sg*e0i, d1i=sg*e0r;
    xr[0]=c0r+c1r; xi[0]=c0i+c1i;
    xr[2]=d0r+d1r; xi[2]=d0i+d1i;
    xr[4]=c0r-c1r; xi[4]=c0i-c1i;
    xr[6]=d0r-d1r; xi[6]=d0i-d1i;
  }
  { // odd outputs: DFT4(t0,b1,b2,b3) -> X1,X3,X5,X7
    float c0r=t0r+b2r, c0i=t0i+b2i;
    float c1r=b1r+b3r, c1i=b1i+b3i;
    float d0r=t0r-b2r, d0i=t0i-b2i;
    float e0r=b1r-b3r, e0i=b1i-b3i;
    float d1r=-sg*e0i, d1i=sg*e0r;
    xr[1]=c0r+c1r; xi[1]=c0i+c1i;
    xr[3]=d0r+d1r; xi[3]=d0i+d1i;
    xr[5]=c0r-c1r; xi[5]=c0i-c1i;
    xr[7]=d0r-d1r; xi[7]=d0i-d1i;
  }
}

// One radix-8 butterfly pass on padded LDS (in-place). twr/twi store the
// FORWARD twiddles exp(-i*theta); inverse uses conjugate.
template<int SGN, bool TW>
__device__ __forceinline__ void fft_stage(float* re, float* im, int a0, int step,
                                          const float* twr, const float* twi) {
  float xr[8], xi[8];
#pragma unroll
  for (int j = 0; j < 8; ++j) { xr[j] = re[a0 + step*j]; xi[j] = im[a0 + step*j]; }
  dft8<SGN>(xr, xi);
  if (TW) {
#pragma unroll
    for (int r = 1; r < 8; ++r) {
      float wr = twr[r];
      float wi = (SGN < 0) ? twi[r] : -twi[r];
      float zr = xr[r]*wr - xi[r]*wi;
      float zi = xr[r]*wi + xi[r]*wr;
      xr[r] = zr; xi[r] = zi;
    }
  }
#pragma unroll
  for (int r = 0; r < 8; ++r) { re[a0 + step*r] = xr[r]; im[a0 + step*r] = xi[r]; }
}

__device__ __forceinline__ int drev(int x) {   // base-8 digit reversal of 9-bit idx
  return ((x & 7) << 6) | (x & 56) | (x >> 6);
}

// ---------------------------------------------------------------- scan kernel
// 1 block = 1 batch row, 64 threads (one wave). Lane l owns 8 elements.
// Layout P (register layout for h/u/out): lane l, reg j <-> natural index
// base(l)+j, base = ((l&7)<<6)|(l&56).  LDS addressing pad(n)=n+(n>>3).
__global__ __launch_bounds__(64) void urnn_scan(
    const float* __restrict__ xp,    // [MROWS][1024]  (re | im halves)
    const float* __restrict__ h0,    // [BB][1024]
    const float* __restrict__ b_h,
    const float* __restrict__ d1, const float* __restrict__ d2, const float* __restrict__ d3,
    const float* __restrict__ r1re, const float* __restrict__ r1im,
    const float* __restrict__ r2re, const float* __restrict__ r2im,
    const int* __restrict__ perm,
    float* __restrict__ outs,        // [MROWS][1024]
    float* __restrict__ hid)         // [BB][1024]
{
  __shared__ float Ar[576], Ai[576], Br[576], Bi[576];
  const int l = threadIdx.x;
  const int b = blockIdx.x;
  const int base = ((l & 7) << 6) | (l & 56);
  const float PI2 = 6.28318530717958647692f;

  // ---- loop-invariant per-lane constants ----
  float e1r[8], e1i[8], e2r[8], e2i[8], e3r[8], e3i[8];
  float v1r[8], v1i[8], v2r[8], v2i[8], bh[8];
  int gidx[8];
  float twAr[8], twAi[8], twBr[8], twBi[8];

#pragma unroll
  for (int j = 0; j < 8; ++j) {
    int n = base + j;                     // layout-P natural index
    float sn, cn;
    sincosf(d1[n], &sn, &cn); e1r[j] = cn; e1i[j] = sn;
    sincosf(d3[n], &sn, &cn); e3r[j] = cn * (1.f/512.f); e3i[j] = sn * (1.f/512.f);
    v2r[j] = r2re[n]; v2i[j] = r2im[n];
    bh[j]  = b_h[n];
    int k = 8*l + j;                      // frequency-phase index (positions 8l+j)
    sincosf(d2[k], &sn, &cn); e2r[j] = cn; e2i[j] = sn;
    int dk = drev(k);
    v1r[j] = r1re[dk]; v1i[j] = r1im[dk];
    int dpk = drev(perm[k]);
    gidx[j] = dpk + (dpk >> 3);           // padded gather address
  }
  twAr[0] = 1.f; twAi[0] = 0.f; twBr[0] = 1.f; twBi[0] = 0.f;
#pragma unroll
  for (int r = 1; r < 8; ++r) {
    float sa, ca, sb, cb;
    sincosf(-PI2 * (float)(l * r)       * (1.f/512.f), &sa, &ca);
    sincosf(-PI2 * (float)((l & 7) * r) * (1.f/64.f),  &sb, &cb);
    twAr[r] = ca; twAi[r] = sa;
    twBr[r] = cb; twBi[r] = sb;
  }
  // Householder normalizers (constant over time)
  float s1 = 0.f, s2 = 0.f;
#pragma unroll
  for (int j = 0; j < 8; ++j) {
    s1 += v1r[j]*v1r[j] + v1i[j]*v1i[j];
    s2 += v2r[j]*v2r[j] + v2i[j]*v2i[j];
  }
  for (int m = 32; m; m >>= 1) { s1 += __shfl_xor(s1, m, 64); s2 += __shfl_xor(s2, m, 64); }
  const float fac1 = 2.f / s1, fac2 = 2.f / s2;

  // ---- initial hidden state (layout P) ----
  float hr[8], hi[8];
  {
    const float* h0p = h0 + (size_t)b * 1024;
    float4 t0 = *(const float4*)(h0p + base);
    float4 t1 = *(const float4*)(h0p + base + 4);
    float4 t2 = *(const float4*)(h0p + 512 + base);
    float4 t3 = *(const float4*)(h0p + 512 + base + 4);
    hr[0]=t0.x; hr[1]=t0.y; hr[2]=t0.z; hr[3]=t0.w;
    hr[4]=t1.x; hr[5]=t1.y; hr[6]=t1.z; hr[7]=t1.w;
    hi[0]=t2.x; hi[1]=t2.y; hi[2]=t2.z; hi[3]=t2.w;
    hi[4]=t3.x; hi[5]=t3.y; hi[6]=t3.z; hi[7]=t3.w;
  }

  const int addr0 = 72*(l & 7) + 9*(l >> 3);   // pad(base+j), step 1 in j
  const int aA    = l + (l >> 3);              // stage A: pad(l+64j),   step 72
  const int aB    = 72*(l >> 3) + (l & 7);     // stage B: pad(64a+b+8j),step 9
  const int aC    = 9*l;                       // stage C: pad(8l+j),    step 1
  const int p5    = 9*(l >> 3) + (l & 7);      // phase 5: pad(dr(base+j)), step 72

  for (int t = 0; t < TT; ++t) {
    // prefetch u for this step (consumed at phase 6)
    const float* xrow = xp + ((size_t)(b*TT + t)) * 1024;
    float ur[8], ui[8];
    {
      float4 t0 = *(const float4*)(xrow + base);
      float4 t1 = *(const float4*)(xrow + base + 4);
      float4 t2 = *(const float4*)(xrow + 512 + base);
      float4 t3 = *(const float4*)(xrow + 512 + base + 4);
      ur[0]=t0.x; ur[1]=t0.y; ur[2]=t0.z; ur[3]=t0.w;
      ur[4]=t1.x; ur[5]=t1.y; ur[6]=t1.z; ur[7]=t1.w;
      ui[0]=t2.x; ui[1]=t2.y; ui[2]=t2.z; ui[3]=t2.w;
      ui[4]=t3.x; ui[5]=t3.y; ui[6]=t3.z; ui[7]=t3.w;
    }

    // phase 0: s = h * e1 -> LDS A (natural order)
#pragma unroll
    for (int j = 0; j < 8; ++j) {
      Ar[addr0 + j] = hr[j]*e1r[j] - hi[j]*e1i[j];
      Ai[addr0 + j] = hr[j]*e1i[j] + hi[j]*e1r[j];
    }
    __syncthreads();
    // forward FFT: stages A, B in LDS
    fft_stage<-1, true>(Ar, Ai, aA, 72, twAr, twAi);
    __syncthreads();
    fft_stage<-1, true>(Ar, Ai, aB, 9, twBr, twBi);
    __syncthreads();
    // stage C in registers; fuse reflection 1
    float sr[8], si[8];
#pragma unroll
    for (int j = 0; j < 8; ++j) { sr[j] = Ar[aC + j]; si[j] = Ai[aC + j]; }
    dft8<-1>(sr, si);
    {
      float dre = 0.f, dim_ = 0.f;
#pragma unroll
      for (int j = 0; j < 8; ++j) {
        dre  += sr[j]*v1r[j] + si[j]*v1i[j];
        dim_ += si[j]*v1r[j] - sr[j]*v1i[j];
      }
      for (int m = 32; m; m >>= 1) { dre += __shfl_xor(dre, m, 64); dim_ += __shfl_xor(dim_, m, 64); }
      float cr = fac1*dre, ci = fac1*dim_;
#pragma unroll
      for (int j = 0; j < 8; ++j) {
        sr[j] -= cr*v1r[j] - ci*v1i[j];
        si[j] -= cr*v1i[j] + ci*v1r[j];
      }
    }
#pragma unroll
    for (int j = 0; j < 8; ++j) { Ar[aC + j] = sr[j]; Ai[aC + j] = si[j]; }
    __syncthreads();
    // phase 3: permutation gather + e2 -> LDS B (natural freq order)
#pragma unroll
    for (int j = 0; j < 8; ++j) {
      float gr = Ar[gidx[j]], gi = Ai[gidx[j]];
      Br[aC + j] = gr*e2r[j] - gi*e2i[j];
      Bi[aC + j] = gr*e2i[j] + gi*e2r[j];
    }
    __syncthreads();
    // inverse FFT (1/512 folded into e3)
    fft_stage<+1, true>(Br, Bi, aA, 72, twAr, twAi);
    __syncthreads();
    fft_stage<+1, true>(Br, Bi, aB, 9, twBr, twBi);
    __syncthreads();
    fft_stage<+1, false>(Br, Bi, aC, 1, twBr, twBi);
    __syncthreads();
    // phase 5: read back in layout P, reflection 2 in registers
    float yr[8], yi[8];
#pragma unroll
    for (int j = 0; j < 8; ++j) { yr[j] = Br[p5 + 72*j]; yi[j] = Bi[p5 + 72*j]; }
    {
      float dre = 0.f, dim_ = 0.f;
#pragma unroll
      for (int j = 0; j < 8; ++j) {
        dre  += yr[j]*v2r[j] + yi[j]*v2i[j];
        dim_ += yi[j]*v2r[j] - yr[j]*v2i[j];
      }
      for (int m = 32; m; m >>= 1) { dre += __shfl_xor(dre, m, 64); dim_ += __shfl_xor(dim_, m, 64); }
      float cr = fac2*dre, ci = fac2*dim_;
#pragma unroll
      for (int j = 0; j < 8; ++j) {
        yr[j] -= cr*v2r[j] - ci*v2i[j];
        yi[j] -= cr*v2i[j] + ci*v2r[j];
      }
    }
    // phase 6: * e3 (incl. 1/512), + u, modReLU -> new h; store outs row
#pragma unroll
    for (int j = 0; j < 8; ++j) {
      float fr = yr[j]*e3r[j] - yi[j]*e3i[j];
      float fi = yr[j]*e3i[j] + yi[j]*e3r[j];
      float pr = ur[j] + fr, pi = ui[j] + fi;
      float nrm = sqrtf(pr*pr + pi*pi);
      float sc  = fmaxf(nrm + bh[j], 0.f) / (nrm + 1e-6f);
      hr[j] = pr*sc; hi[j] = pi*sc;
    }
    float* orow = outs + ((size_t)(b*TT + t)) * 1024;
    *(float4*)(orow + base)       = make_float4(hr[0],hr[1],hr[2],hr[3]);
    *(float4*)(orow + base + 4)   = make_float4(hr[4],hr[5],hr[6],hr[7]);
    *(float4*)(orow + 512 + base)     = make_float4(hi[0],hi[1],hi[2],hi[3]);
    *(float4*)(orow + 512 + base + 4) = make_float4(hi[4],hi[5],hi[6],hi[7]);
  }

  // final hidden state
  float* hrow = hid + (size_t)b * 1024;
  *(float4*)(hrow + base)       = make_float4(hr[0],hr[1],hr[2],hr[3]);
  *(float4*)(hrow + base + 4)   = make_float4(hr[4],hr[5],hr[6],hr[7]);
  *(float4*)(hrow + 512 + base)     = make_float4(hi[0],hi[1],hi[2],hi[3]);
  *(float4*)(hrow + 512 + base + 4) = make_float4(hi[4],hi[5],hi[6],hi[7]);
}

// ---------------------------------------------------------------- fp32 GEMM
// C[m][n] = sum_k A[m][k] * Bw[n][k] (+ bias[n]).  M%64==0, N%64==0, K%16==0.
#define BM 64
#define BN 64
#define BKK 16
#define LDP 68

__global__ __launch_bounds__(256) void gemm_nt(const float* __restrict__ A,
                                               const float* __restrict__ Bw,
                                               const float* __restrict__ bias,
                                               float* __restrict__ C,
                                               int M, int N, int K) {
  __shared__ __align__(16) float As[BKK][LDP];
  __shared__ __align__(16) float Bs[BKK][LDP];
  const int t  = threadIdx.x;
  const int tm = t >> 4, tn = t & 15;
  const int bm = blockIdx.y * BM, bn = blockIdx.x * BN;
  const int lrow = t >> 2, lk = (t & 3) * 4;
  const float* Ap = A  + (size_t)(bm + lrow) * K + lk;
  const float* Bp = Bw + (size_t)(bn + lrow) * K + lk;
  float acc[4][4] = {};
  for (int k0 = 0; k0 < K; k0 += BKK) {
    float4 av = *(const float4*)(Ap + k0);
    float4 bv = *(const float4*)(Bp + k0);
    As[lk+0][lrow] = av.x; As[lk+1][lrow] = av.y; As[lk+2][lrow] = av.z; As[lk+3][lrow] = av.w;
    Bs[lk+0][lrow] = bv.x; Bs[lk+1][lrow] = bv.y; Bs[lk+2][lrow] = bv.z; Bs[lk+3][lrow] = bv.w;
    __syncthreads();
#pragma unroll
    for (int kk = 0; kk < BKK; ++kk) {
      float4 a4 = *(const float4*)&As[kk][tm*4];
      float4 b4 = *(const float4*)&Bs[kk][tn*4];
      acc[0][0] += a4.x*b4.x; acc[0][1] += a4.x*b4.y; acc[0][2] += a4.x*b4.z; acc[0][3] += a4.x*b4.w;
      acc[1][0] += a4.y*b4.x; acc[1][1] += a4.y*b4.y; acc[1][2] += a4.y*b4.z; acc[1][3] += a4.y*b4.w;
      acc[2][0] += a4.z*b4.x; acc[2][1] += a4.z*b4.y; acc[2][2] += a4.z*b4.z; acc[2][3] += a4.z*b4.w;
      acc[3][0] += a4.w*b4.x; acc[3][1] += a4.w*b4.y; acc[3][2] += a4.w*b4.z; acc[3][3] += a4.w*b4.w;
    }
    __syncthreads();
  }
  const int col = bn + tn*4;
  float b0 = 0.f, b1 = 0.f, b2 = 0.f, b3 = 0.f;
  if (bias) { b0 = bias[col]; b1 = bias[col+1]; b2 = bias[col+2]; b3 = bias[col+3]; }
#pragma unroll
  for (int i = 0; i < 4; ++i) {
    float* crow = C + (size_t)(bm + tm*4 + i) * N + col;
    crow[0] = acc[i][0] + b0;
    crow[1] = acc[i][1] + b1;
    crow[2] = acc[i][2] + b2;
    crow[3] = acc[i][3] + b3;
  }
}

// ---------------------------------------------------------------- launch
extern "C" void kernel_launch(void* const* d_in, const int* in_sizes, int n_in,
                              void* d_out, int out_size, void* d_ws, size_t ws_size,
                              hipStream_t stream) {
  const float* x    = (const float*)d_in[0];
  const float* h0   = (const float*)d_in[1];
  const float* itoh = (const float*)d_in[2];
  const float* fcw  = (const float*)d_in[3];
  const float* fcb  = (const float*)d_in[4];
  const float* bh   = (const float*)d_in[5];
  const float* d1   = (const float*)d_in[6];
  const float* d2   = (const float*)d_in[7];
  const float* d3   = (const float*)d_in[8];
  const float* r1re = (const float*)d_in[9];
  const float* r1im = (const float*)d_in[10];
  const float* r2re = (const float*)d_in[11];
  const float* r2im = (const float*)d_in[12];
  const int*   perm = (const int*)d_in[13];

  float* out  = (float*)d_out;
  float* xp   = (float*)d_ws;                       // [MROWS][1024]
  float* outs = xp + (size_t)MROWS * 1024;          // [MROWS][1024]
  float* hid  = out + (size_t)MROWS * OUTD;         // [BB][1024]

  // xp = x @ itoh_w^T
  dim3 g1(1024 / BN, MROWS / BM);
  gemm_nt<<<g1, 256, 0, stream>>>(x, itoh, nullptr, xp, MROWS, 1024, IND);
  // sequential unitary-RNN scan (one block per batch row)
  urnn_scan<<<dim3(BB), dim3(64), 0, stream>>>(xp, h0, bh, d1, d2, d3,
                                               r1re, r1im, r2re, r2im, perm,
                                               outs, hid);
  // outputs = outs @ fc_w^T + fc_b
  dim3 g2(OUTD / BN, MROWS / BM);
  gemm_nt<<<g2, 256, 0, stream>>>(outs, fcw, fcb, out, MROWS, OUTD, 1024);
}

// Round 9
// 1963.315 us; speedup vs baseline: 1.3488x; 1.3488x over previous
//
#include <hip/hip_runtime.h>
#include <hip/hip_bf16.h>
#include <math.h>

#define BB 64
#define TT 512
#define IND 256
#define OUTD 256
#define MROWS (BB*TT)   // 32768

typedef __attribute__((ext_vector_type(8))) short short8v;
typedef __attribute__((ext_vector_type(4))) float f32x4;

__device__ __forceinline__ float fast_rcp(float x) {
#if __has_builtin(__builtin_amdgcn_rcpf)
  return __builtin_amdgcn_rcpf(x);
#else
  return 1.0f / x;
#endif
}
__device__ __forceinline__ float fast_sqrt(float x) {
#if __has_builtin(__builtin_amdgcn_sqrtf)
  return __builtin_amdgcn_sqrtf(x);
#else
  return sqrtf(x);
#endif
}

// ---------------------------------------------------------------- 8-point DFT
template<int SGN>
__device__ __forceinline__ void dft8(float xr[8], float xi[8]) {
  const float s = 0.70710678118654752440f;
  const float sg = (float)SGN;
  float a0r=xr[0]+xr[4], a0i=xi[0]+xi[4];
  float a1r=xr[1]+xr[5], a1i=xi[1]+xi[5];
  float a2r=xr[2]+xr[6], a2i=xi[2]+xi[6];
  float a3r=xr[3]+xr[7], a3i=xi[3]+xi[7];
  float t0r=xr[0]-xr[4], t0i=xi[0]-xi[4];
  float t1r=xr[1]-xr[5], t1i=xi[1]-xi[5];
  float t2r=xr[2]-xr[6], t2i=xi[2]-xi[6];
  float t3r=xr[3]-xr[7], t3i=xi[3]-xi[7];
  float b1r = s*(t1r - sg*t1i), b1i = s*(sg*t1r + t1i);
  float b2r = -sg*t2i,          b2i = sg*t2r;
  float b3r = -s*(t3r + sg*t3i), b3i = s*(sg*t3r - t3i);
  {
    float c0r=a0r+a2r, c0i=a0i+a2i;
    float c1r=a1r+a3r, c1i=a1i+a3i;
    float d0r=a0r-a2r, d0i=a0i-a2i;
    float e0r=a1r-a3r, e0i=a1i-a3i;
    float d1r=-sg*e0i, d1i=sg*e0r;
    xr[0]=c0r+c1r; xi[0]=c0i+c1i;
    xr[2]=d0r+d1r; xi[2]=d0i+d1i;
    xr[4]=c0r-c1r; xi[4]=c0i-c1i;
    xr[6]=d0r-d1r; xi[6]=d0i-d1i;
  }
  {
    float c0r=t0r+b2r, c0i=t0i+b2i;
    float c1r=b1r+b3r, c1i=b1i+b3i;
    float d0r=t0r-b2r, d0i=t0i-b2i;
    float e0r=b1r-b3r, e0i=b1i-b3i;
    float d1r=-sg*e0i, d1i=sg*e0r;
    xr[1]=c0r+c1r; xi[1]=c0i+c1i;
    xr[3]=d0r+d1r; xi[3]=d0i+d1i;
    xr[5]=c0r-c1r; xi[5]=c0i-c1i;
    xr[7]=d0r-d1r; xi[7]=d0i-d1i;
  }
}

__device__ __forceinline__ void cmulp(float& ar, float& ai, float br, float bi) {
  float tr = ar*br - ai*bi;
  float ti = ar*bi + ai*br;
  ar = tr; ai = ti;
}

__device__ __forceinline__ void allred2(float& a, float& b) {
#pragma unroll
  for (int m = 32; m; m >>= 1) { a += __shfl_xor(a, m, 64); b += __shfl_xor(b, m, 64); }
}

// Full 512-pt FFT (3x radix-8) in registers; LDS only for the two 8x8
// transposes. Single wave: no barriers (same-wave LDS ops are pipe-ordered).
// Input: reg d, lane l <-> n = 64d + a; a-label encoded in tA (W512^{a*r})
// and w1 = 10*(a&7)+(a>>3). Output: reg r, lane l <-> 64r + sigma(l),
// sigma(l)=8*(l&7)+(l>>3). Exchange buffers padded: run g at float2 idx 10g.
template<int SGN>
__device__ __forceinline__ void fft3(float xr[8], float xi[8],
    const float (&tAr)[8], const float (&tAi)[8],
    const float (&tBr)[8], const float (&tBi)[8],
    int w1, float2* XB, float2* YB, int l) {
  dft8<SGN>(xr, xi);
#pragma unroll
  for (int r = 1; r < 8; ++r) cmulp(xr[r], xi[r], tAr[r], tAi[r]);
#pragma unroll
  for (int d = 0; d < 8; ++d) XB[w1 + 80*d] = make_float2(xr[d], xi[d]);
  {
    const float4* rp = (const float4*)XB + 5*l;
#pragma unroll
    for (int q = 0; q < 4; ++q) {
      float4 v = rp[q];
      xr[2*q]=v.x; xi[2*q]=v.y; xr[2*q+1]=v.z; xi[2*q+1]=v.w;
    }
  }
  dft8<SGN>(xr, xi);
#pragma unroll
  for (int r = 1; r < 8; ++r) cmulp(xr[r], xi[r], tBr[r], (SGN<0)?tBi[r]:-tBi[r]);
  const int w2 = 80*(l>>3) + (l&7);
#pragma unroll
  for (int d = 0; d < 8; ++d) YB[w2 + 10*d] = make_float2(xr[d], xi[d]);
  {
    const float4* rp = (const float4*)YB + 5*l;
#pragma unroll
    for (int q = 0; q < 4; ++q) {
      float4 v = rp[q];
      xr[2*q]=v.x; xi[2*q]=v.y; xr[2*q+1]=v.z; xi[2*q+1]=v.w;
    }
  }
  dft8<SGN>(xr, xi);
}

// ---------------------------------------------------------------- scan kernel
// 1 block = 1 batch row = 1 wave, 8 complex elems/lane in VGPRs.
// h resident in layout R' (reg r, lane l <-> 64r + sigma(l)); both FFTs emit
// R', forward consumes R' via a=sigma(l) twiddles -> no per-step lane permute.
// Reflections deferred via linearity; W1 = IFFTraw(P(v1)e2) precomputed.
// SPLIT=1: emit outs as bf16 hi/lo pair (for MFMA GEMM2). SPLIT=0: fp32 outs.
template<int SPLIT>
__global__ __launch_bounds__(64, 1) void urnn_scan(
    const float* __restrict__ xp,
    const float* __restrict__ h0,
    const float* __restrict__ b_h,
    const float* __restrict__ d1, const float* __restrict__ d2, const float* __restrict__ d3,
    const float* __restrict__ r1re, const float* __restrict__ r1im,
    const float* __restrict__ r2re, const float* __restrict__ r2im,
    const int* __restrict__ perm,
    float* __restrict__ outs,                  // SPLIT=0
    __hip_bfloat16* __restrict__ outs_hi,      // SPLIT=1
    __hip_bfloat16* __restrict__ outs_lo,      // SPLIT=1
    float* __restrict__ hid)
{
  __shared__ __align__(16) float2 XB[640], YB[640], NATB[512]; // 14336 B
  const int l = threadIdx.x;
  const int b = blockIdx.x;
  const int sl = 8*(l&7) + (l>>3);
  const float PI2 = 6.28318530717958647692f;

  float tAFr[8], tAFi[8], tAIr[8], tAIi[8], tBr[8], tBi[8];
  tAFr[0]=1.f; tAFi[0]=0.f; tAIr[0]=1.f; tAIi[0]=0.f; tBr[0]=1.f; tBi[0]=0.f;
#pragma unroll
  for (int r = 1; r < 8; ++r) {
    float sa, ca;
    sincosf(-PI2*(float)(sl*r)*(1.f/512.f), &sa, &ca); tAFr[r]=ca; tAFi[r]=sa;
    sincosf( PI2*(float)(l*r) *(1.f/512.f), &sa, &ca); tAIr[r]=ca; tAIi[r]=sa;
    sincosf(-PI2*(float)((l&7)*r)*(1.f/64.f), &sa, &ca); tBr[r]=ca; tBi[r]=sa;
  }
  const int w1F = 10*(l>>3) + (l&7);
  const int w1I = 10*(l&7) + (l>>3);

  float e1r[8], e1i[8], e2r_[8], e2i_[8], e3r_[8], e3i_[8];
  float v1r[8], v1i[8], v2r[8], v2i[8], bh[8];
  int gk[8];
#pragma unroll
  for (int j = 0; j < 8; ++j) {
    float sn, cn;
    int nQ = 64*j + l;
    int nR = 64*j + sl;
    sincosf(d1[nR], &sn, &cn); e1r[j]=cn; e1i[j]=sn;
    sincosf(d2[nQ], &sn, &cn); e2r_[j]=cn; e2i_[j]=sn;
    sincosf(d3[nR], &sn, &cn); e3r_[j]=cn*(1.f/512.f); e3i_[j]=sn*(1.f/512.f);
    v1r[j]=r1re[nR]; v1i[j]=r1im[nR];
    v2r[j]=r2re[nR]; v2i[j]=r2im[nR];
    bh[j]=b_h[nR];
    gk[j]=perm[nQ];
  }
  float s1=0.f, s2=0.f;
#pragma unroll
  for (int j = 0; j < 8; ++j) {
    s1 += v1r[j]*v1r[j] + v1i[j]*v1i[j];
    s2 += v2r[j]*v2r[j] + v2i[j]*v2i[j];
  }
  allred2(s1, s2);
  const float fac1 = 2.f/s1, fac2 = 2.f/s2;

  float W1r[8], W1i[8];
  {
#pragma unroll
    for (int j = 0; j < 8; ++j)
      NATB[64*j + l] = make_float2(r1re[64*j + l], r1im[64*j + l]);
    float tr[8], ti[8];
#pragma unroll
    for (int j = 0; j < 8; ++j) {
      float2 g = NATB[gk[j]];
      tr[j] = g.x*e2r_[j] - g.y*e2i_[j];
      ti[j] = g.x*e2i_[j] + g.y*e2r_[j];
    }
    fft3<+1>(tr, ti, tAIr, tAIi, tBr, tBi, w1I, XB, YB, l);
#pragma unroll
    for (int r = 0; r < 8; ++r) { W1r[r]=tr[r]; W1i[r]=ti[r]; }
  }
  float q12r=0.f, q12i=0.f;
#pragma unroll
  for (int r = 0; r < 8; ++r) {
    q12r += W1r[r]*v2r[r] + W1i[r]*v2i[r];
    q12i += W1i[r]*v2r[r] - W1r[r]*v2i[r];
  }
  allred2(q12r, q12i);

  float hr[8], hi[8];
  {
    const float* hp = h0 + (size_t)b*1024 + sl;
#pragma unroll
    for (int r = 0; r < 8; ++r) { hr[r]=hp[64*r]; hi[r]=hp[512+64*r]; }
  }

  const float* up = xp + (size_t)b*TT*1024 + sl;
  float* op = SPLIT ? nullptr : (outs + (size_t)b*TT*1024 + sl);
  __hip_bfloat16* oph = SPLIT ? (outs_hi + (size_t)b*TT*1024 + sl) : nullptr;
  __hip_bfloat16* opl = SPLIT ? (outs_lo + (size_t)b*TT*1024 + sl) : nullptr;

  for (int t = 0; t < TT; ++t) {
    float ur[8], ui[8];
#pragma unroll
    for (int r = 0; r < 8; ++r) { ur[r]=up[64*r]; ui[r]=up[512+64*r]; }

    float xr[8], xi[8];
#pragma unroll
    for (int r = 0; r < 8; ++r) {
      xr[r] = hr[r]*e1r[r] - hi[r]*e1i[r];
      xi[r] = hr[r]*e1i[r] + hi[r]*e1r[r];
    }
    fft3<-1>(xr, xi, tAFr, tAFi, tBr, tBi, w1F, XB, YB, l);
#pragma unroll
    for (int r = 0; r < 8; ++r) NATB[sl + 64*r] = make_float2(xr[r], xi[r]);
    float2 g[8];
#pragma unroll
    for (int j = 0; j < 8; ++j) g[j] = NATB[gk[j]];
    float c_re=0.f, c_im=0.f;
#pragma unroll
    for (int r = 0; r < 8; ++r) {
      c_re += xr[r]*v1r[r] + xi[r]*v1i[r];
      c_im += xi[r]*v1r[r] - xr[r]*v1i[r];
    }
    allred2(c_re, c_im);
    float yr[8], yi[8];
#pragma unroll
    for (int j = 0; j < 8; ++j) {
      yr[j] = g[j].x*e2r_[j] - g[j].y*e2i_[j];
      yi[j] = g[j].x*e2i_[j] + g[j].y*e2r_[j];
    }
    fft3<+1>(yr, yi, tAIr, tAIi, tBr, tBi, w1I, XB, YB, l);
    float D_re=0.f, D_im=0.f;
#pragma unroll
    for (int r = 0; r < 8; ++r) {
      D_re += yr[r]*v2r[r] + yi[r]*v2i[r];
      D_im += yi[r]*v2r[r] - yr[r]*v2i[r];
    }
    allred2(D_re, D_im);
    const float cr = fac1*c_re, ci = fac1*c_im;
    const float C2r = fac2*(D_re - (cr*q12r - ci*q12i));
    const float C2i = fac2*(D_im - (cr*q12i + ci*q12r));
#pragma unroll
    for (int r = 0; r < 8; ++r) {
      float tr = yr[r] - (cr*W1r[r] - ci*W1i[r]) - (C2r*v2r[r] - C2i*v2i[r]);
      float ti = yi[r] - (cr*W1i[r] + ci*W1r[r]) - (C2r*v2i[r] + C2i*v2r[r]);
      float fr = tr*e3r_[r] - ti*e3i_[r];
      float fi = tr*e3i_[r] + ti*e3r_[r];
      float pr = ur[r] + fr, pi = ui[r] + fi;
      float nrm = fast_sqrt(pr*pr + pi*pi);
      float sc  = fmaxf(nrm + bh[r], 0.f) * fast_rcp(nrm + 1e-6f);
      float nr_ = pr*sc, ni_ = pi*sc;
      if (SPLIT) {
        __hip_bfloat16 h1 = __float2bfloat16(nr_);
        __hip_bfloat16 h2 = __float2bfloat16(ni_);
        oph[64*r]       = h1;
        oph[512 + 64*r] = h2;
        opl[64*r]       = __float2bfloat16(nr_ - __bfloat162float(h1));
        opl[512 + 64*r] = __float2bfloat16(ni_ - __bfloat162float(h2));
      } else {
        op[64*r] = nr_; op[512 + 64*r] = ni_;
      }
      hr[r] = nr_; hi[r] = ni_;
    }
    up += 1024;
    if (SPLIT) { oph += 1024; opl += 1024; } else { op += 1024; }
  }
  {
    float* hp = hid + (size_t)b*1024 + sl;
#pragma unroll
    for (int r = 0; r < 8; ++r) { hp[64*r]=hr[r]; hp[512+64*r]=hi[r]; }
  }
}

// ---------------------------------------------------------------- bf16 split
// hi = bf16(v); lo = bf16(v - hi).  (hi+lo) reproduces v to ~2^-18 rel.
__global__ __launch_bounds__(256) void split_bf16(const float* __restrict__ in,
                                                  __hip_bfloat16* __restrict__ hi,
                                                  __hip_bfloat16* __restrict__ lo,
                                                  int n4) {
  for (int i = blockIdx.x*blockDim.x + threadIdx.x; i < n4; i += gridDim.x*blockDim.x) {
    float4 v = ((const float4*)in)[i];
    float vv[4] = {v.x, v.y, v.z, v.w};
#pragma unroll
    for (int j = 0; j < 4; ++j) {
      __hip_bfloat16 h = __float2bfloat16(vv[j]);
      hi[4*i + j] = h;
      lo[4*i + j] = __float2bfloat16(vv[j] - __bfloat162float(h));
    }
  }
}

// ---------------------------------------------------------------- MFMA GEMM
// C[m][n] = sum_k (Ahi+Alo)[m][k]*(Bhi+Blo)[n][k] (+bias[n]), via 3 products
// Ahi*Bhi + Ahi*Blo + Alo*Bhi (lo*lo dropped, ~2^-36 rel).
// 128x128 tile, 4 waves (2x2 of 64x64), BK=32 (one 16x16x32 MFMA per frag).
// Fragment layouts (m89/m91-verified): A row=l&15 k=8*(l>>4)+i; B col=l&15
// same k; C/D col=l&15 row=(l>>4)*4+reg. LDS rows padded to 40 shorts (80 B:
// 16B-aligned, ~2-way read banks). M%128==0, N%128==0, K%32==0.
__global__ __launch_bounds__(256, 1) void gemm_mfma_nt(
    const ushort* __restrict__ Ahi, const ushort* __restrict__ Alo,
    const ushort* __restrict__ Bhi, const ushort* __restrict__ Blo,
    const float* __restrict__ bias, float* __restrict__ C,
    int M, int N, int K)
{
  __shared__ __align__(16) ushort As[128*40];
  __shared__ __align__(16) ushort Bs[128*40];
  const int t  = threadIdx.x;
  const int l  = t & 63;
  const int w  = t >> 6;
  const int wr = w >> 1, wc = w & 1;
  const int bm = blockIdx.y * 128, bn = blockIdx.x * 128;
  const int srow = t >> 1, sseg = t & 1;
  const int lr = l & 15;
  const int lk = (l >> 4) * 8;

  f32x4 acc[4][4];
#pragma unroll
  for (int fm = 0; fm < 4; ++fm)
#pragma unroll
    for (int fn = 0; fn < 4; ++fn) {
      f32x4 z = {0.f, 0.f, 0.f, 0.f};
      acc[fm][fn] = z;
    }

  const ushort* APs[3] = {Ahi, Ahi, Alo};
  const ushort* BPs[3] = {Bhi, Blo, Bhi};

  // rule #20: fully unroll so APs/BPs indexing is compile-time-constant
  // (runtime-indexed pointer arrays can drop to scratch).
#pragma unroll
  for (int ph = 0; ph < 3; ++ph) {
    const ushort* Ap = APs[ph] + (size_t)(bm + srow) * K + sseg * 16;
    const ushort* Bp = BPs[ph] + (size_t)(bn + srow) * K + sseg * 16;
    for (int k0 = 0; k0 < K; k0 += 32) {
      short8v a0 = *(const short8v*)(Ap + k0);
      short8v a1 = *(const short8v*)(Ap + k0 + 8);
      short8v b0 = *(const short8v*)(Bp + k0);
      short8v b1 = *(const short8v*)(Bp + k0 + 8);
      *(short8v*)&As[srow*40 + sseg*16]     = a0;
      *(short8v*)&As[srow*40 + sseg*16 + 8] = a1;
      *(short8v*)&Bs[srow*40 + sseg*16]     = b0;
      *(short8v*)&Bs[srow*40 + sseg*16 + 8] = b1;
      __syncthreads();
      short8v bf[4];
#pragma unroll
      for (int fn = 0; fn < 4; ++fn)
        bf[fn] = *(const short8v*)&Bs[(wc*64 + fn*16 + lr)*40 + lk];
#pragma unroll
      for (int fm = 0; fm < 4; ++fm) {
        short8v af = *(const short8v*)&As[(wr*64 + fm*16 + lr)*40 + lk];
#pragma unroll
        for (int fn = 0; fn < 4; ++fn)
          acc[fm][fn] = __builtin_amdgcn_mfma_f32_16x16x32_bf16(af, bf[fn], acc[fm][fn], 0, 0, 0);
      }
      __syncthreads();
    }
  }

  float bv[4] = {0.f, 0.f, 0.f, 0.f};
  if (bias) {
#pragma unroll
    for (int fn = 0; fn < 4; ++fn) bv[fn] = bias[bn + wc*64 + fn*16 + lr];
  }
#pragma unroll
  for (int fm = 0; fm < 4; ++fm)
#pragma unroll
    for (int j = 0; j < 4; ++j) {
      float* crow = C + (size_t)(bm + wr*64 + fm*16 + (l>>4)*4 + j) * N + bn + wc*64 + lr;
#pragma unroll
      for (int fn = 0; fn < 4; ++fn)
        crow[fn*16] = acc[fm][fn][j] + bv[fn];
    }
}

// ---------------------------------------------------------------- fp32 GEMM (fallback)
#define BM 64
#define BN 64
#define BKK 16
#define LDP 68

__global__ __launch_bounds__(256) void gemm_nt(const float* __restrict__ A,
                                               const float* __restrict__ Bw,
                                               const float* __restrict__ bias,
                                               float* __restrict__ C,
                                               int M, int N, int K) {
  __shared__ __align__(16) float As[BKK][LDP];
  __shared__ __align__(16) float Bs[BKK][LDP];
  const int t  = threadIdx.x;
  const int tm = t >> 4, tn = t & 15;
  const int bm = blockIdx.y * BM, bn = blockIdx.x * BN;
  const int lrow = t >> 2, lk = (t & 3) * 4;
  const float* Ap = A  + (size_t)(bm + lrow) * K + lk;
  const float* Bp = Bw + (size_t)(bn + lrow) * K + lk;
  float acc[4][4] = {};
  for (int k0 = 0; k0 < K; k0 += BKK) {
    float4 av = *(const float4*)(Ap + k0);
    float4 bv = *(const float4*)(Bp + k0);
    As[lk+0][lrow] = av.x; As[lk+1][lrow] = av.y; As[lk+2][lrow] = av.z; As[lk+3][lrow] = av.w;
    Bs[lk+0][lrow] = bv.x; Bs[lk+1][lrow] = bv.y; Bs[lk+2][lrow] = bv.z; Bs[lk+3][lrow] = bv.w;
    __syncthreads();
#pragma unroll
    for (int kk = 0; kk < BKK; ++kk) {
      float4 a4 = *(const float4*)&As[kk][tm*4];
      float4 b4 = *(const float4*)&Bs[kk][tn*4];
      acc[0][0] += a4.x*b4.x; acc[0][1] += a4.x*b4.y; acc[0][2] += a4.x*b4.z; acc[0][3] += a4.x*b4.w;
      acc[1][0] += a4.y*b4.x; acc[1][1] += a4.y*b4.y; acc[1][2] += a4.y*b4.z; acc[1][3] += a4.y*b4.w;
      acc[2][0] += a4.z*b4.x; acc[2][1] += a4.z*b4.y; acc[2][2] += a4.z*b4.z; acc[2][3] += a4.z*b4.w;
      acc[3][0] += a4.w*b4.x; acc[3][1] += a4.w*b4.y; acc[3][2] += a4.w*b4.z; acc[3][3] += a4.w*b4.w;
    }
    __syncthreads();
  }
  const int col = bn + tn*4;
  float b0 = 0.f, b1 = 0.f, b2 = 0.f, b3 = 0.f;
  if (bias) { b0 = bias[col]; b1 = bias[col+1]; b2 = bias[col+2]; b3 = bias[col+3]; }
#pragma unroll
  for (int i = 0; i < 4; ++i) {
    float* crow = C + (size_t)(bm + tm*4 + i) * N + col;
    crow[0] = acc[i][0] + b0;
    crow[1] = acc[i][1] + b1;
    crow[2] = acc[i][2] + b2;
    crow[3] = acc[i][3] + b3;
  }
}

// ---------------------------------------------------------------- launch
extern "C" void kernel_launch(void* const* d_in, const int* in_sizes, int n_in,
                              void* d_out, int out_size, void* d_ws, size_t ws_size,
                              hipStream_t stream) {
  const float* x    = (const float*)d_in[0];
  const float* h0   = (const float*)d_in[1];
  const float* itoh = (const float*)d_in[2];
  const float* fcw  = (const float*)d_in[3];
  const float* fcb  = (const float*)d_in[4];
  const float* bh   = (const float*)d_in[5];
  const float* d1   = (const float*)d_in[6];
  const float* d2   = (const float*)d_in[7];
  const float* d3   = (const float*)d_in[8];
  const float* r1re = (const float*)d_in[9];
  const float* r1im = (const float*)d_in[10];
  const float* r2re = (const float*)d_in[11];
  const float* r2im = (const float*)d_in[12];
  const int*   perm = (const int*)d_in[13];

  float* out = (float*)d_out;
  float* hid = out + (size_t)MROWS * OUTD;

  char* wsb = (char*)d_ws;
  // MFMA-path workspace layout (bytes):
  const size_t OFF_XP  = 0;                              // fp32 [M][1024] 128 MB
  const size_t OFF_OH  = OFF_XP  + (size_t)MROWS*1024*4; // bf16 [M][1024]  64 MB
  const size_t OFF_OL  = OFF_OH  + (size_t)MROWS*1024*2;
  const size_t OFF_XH  = OFF_OL  + (size_t)MROWS*1024*2; // bf16 [M][256]   16 MB
  const size_t OFF_XL  = OFF_XH  + (size_t)MROWS*256*2;
  const size_t OFF_IH  = OFF_XL  + (size_t)MROWS*256*2;  // bf16 [1024][256]
  const size_t OFF_IL  = OFF_IH  + (size_t)1024*256*2;
  const size_t OFF_FH  = OFF_IL  + (size_t)1024*256*2;   // bf16 [256][1024]
  const size_t OFF_FL  = OFF_FH  + (size_t)256*1024*2;
  const size_t NEED    = OFF_FL  + (size_t)256*1024*2;   // 304,087,040 B

  float* xp = (float*)(wsb + OFF_XP);

  if (ws_size >= NEED) {
    __hip_bfloat16* oh  = (__hip_bfloat16*)(wsb + OFF_OH);
    __hip_bfloat16* ol  = (__hip_bfloat16*)(wsb + OFF_OL);
    __hip_bfloat16* xh  = (__hip_bfloat16*)(wsb + OFF_XH);
    __hip_bfloat16* xl  = (__hip_bfloat16*)(wsb + OFF_XL);
    __hip_bfloat16* ih  = (__hip_bfloat16*)(wsb + OFF_IH);
    __hip_bfloat16* il  = (__hip_bfloat16*)(wsb + OFF_IL);
    __hip_bfloat16* fh  = (__hip_bfloat16*)(wsb + OFF_FH);
    __hip_bfloat16* fl  = (__hip_bfloat16*)(wsb + OFF_FL);

    split_bf16<<<4096, 256, 0, stream>>>(x,    xh, xl, MROWS*256/4);
    split_bf16<<<256,  256, 0, stream>>>(itoh, ih, il, 1024*256/4);
    split_bf16<<<256,  256, 0, stream>>>(fcw,  fh, fl, 256*1024/4);

    dim3 g1(1024/128, MROWS/128);
    gemm_mfma_nt<<<g1, 256, 0, stream>>>((const ushort*)xh, (const ushort*)xl,
                                         (const ushort*)ih, (const ushort*)il,
                                         nullptr, xp, MROWS, 1024, 256);
    urnn_scan<1><<<dim3(BB), dim3(64), 0, stream>>>(xp, h0, bh, d1, d2, d3,
                                                    r1re, r1im, r2re, r2im, perm,
                                                    nullptr, oh, ol, hid);
    dim3 g2(OUTD/128, MROWS/128);
    gemm_mfma_nt<<<g2, 256, 0, stream>>>((const ushort*)oh, (const ushort*)ol,
                                         (const ushort*)fh, (const ushort*)fl,
                                         fcb, out, MROWS, OUTD, 1024);
  } else {
    // Fallback: fp32 everywhere (proven ws floor 256 MB).
    float* outs = xp + (size_t)MROWS * 1024;
    dim3 g1(1024/BN, MROWS/BM);
    gemm_nt<<<g1, 256, 0, stream>>>(x, itoh, nullptr, xp, MROWS, 1024, IND);
    urnn_scan<0><<<dim3(BB), dim3(64), 0, stream>>>(xp, h0, bh, d1, d2, d3,
                                                    r1re, r1im, r2re, r2im, perm,
                                                    outs, nullptr, nullptr, hid);
    dim3 g2(OUTD/BN, MROWS/BM);
    gemm_nt<<<g2, 256, 0, stream>>>(outs, fcw, fcb, out, MROWS, OUTD, 1024);
  }
}